// Round 1
// baseline (545.598 us; speedup 1.0000x reference)
//
#include <hip/hip_runtime.h>
#include <stdint.h>

#define BB 4
#define TSEQ 512
#define NSEQ 512
#define DD 1024
#define EE 1024
#define HH 16
#define HD 64
// rows: hq = B*3T = 6144, hx = B*N = 2048

typedef __attribute__((ext_vector_type(8))) short bf16x8;
typedef __attribute__((ext_vector_type(4))) float f32x4;

__device__ __forceinline__ unsigned short f2bf(float f) {
    union { float f; uint32_t u; } v; v.f = f;
    uint32_t u = v.u;
    uint32_t r = (u + 0x7fffu + ((u >> 16) & 1u)) >> 16;
    return (unsigned short)r;
}

// ---------------------------------------------------------------------------
// K1: se = silu(emb); eo = se @ W_j + b_j ; split into scale/shift
// grid (8 colchunks, B, 4 branches), block 256
// ---------------------------------------------------------------------------
__global__ __launch_bounds__(256) void adaln_kernel(
    const float* __restrict__ emb,
    const float* __restrict__ adaln_w, const float* __restrict__ adaln_b,
    const float* __restrict__ xf_w, const float* __restrict__ xf_b,
    float* __restrict__ scaleB, float* __restrict__ shiftB)
{
    __shared__ float se[EE];
    int tid = threadIdx.x;
    int chunk = blockIdx.x, b = blockIdx.y, j = blockIdx.z;
    float4 e4 = ((const float4*)(emb + (size_t)b * EE))[tid];
    se[tid * 4 + 0] = e4.x / (1.f + __expf(-e4.x));
    se[tid * 4 + 1] = e4.y / (1.f + __expf(-e4.y));
    se[tid * 4 + 2] = e4.z / (1.f + __expf(-e4.z));
    se[tid * 4 + 3] = e4.w / (1.f + __expf(-e4.w));
    __syncthreads();
    const float* W    = (j < 3) ? (adaln_w + (size_t)j * EE * 2 * DD) : xf_w;
    const float* bias = (j < 3) ? (adaln_b + (size_t)j * 2 * DD) : xf_b;
    int c = chunk * 256 + tid;   // [0, 2048)
    float acc = 0.f;
#pragma unroll 8
    for (int e = 0; e < EE; e++) acc += se[e] * W[(size_t)e * (2 * DD) + c];
    float v = acc + bias[c];
    if (c < DD) scaleB[(size_t)(j * 4 + b) * DD + c] = v;
    else        shiftB[(size_t)(j * 4 + b) * DD + (c - DD)] = v;
}

// ---------------------------------------------------------------------------
// K2: LayerNorm + (1+scale)*x + shift, cast to bf16.  grid 8192 rows, block 256
// rows [0,6144): hq (b-major, branch, t); rows [6144,8192): hx
// ---------------------------------------------------------------------------
__global__ __launch_bounds__(256) void ln_mod_kernel(
    const float* __restrict__ x1, const float* __restrict__ x2,
    const float* __restrict__ x3, const float* __restrict__ xf,
    const float* __restrict__ scaleB, const float* __restrict__ shiftB,
    unsigned short* __restrict__ hq, unsigned short* __restrict__ hx)
{
    __shared__ float rs[4], rq[4];
    int row = blockIdx.x, tid = threadIdx.x;
    const float* src; unsigned short* dst; int sb;
    if (row < 6144) {
        int b = row / 1536, t3 = row % 1536;
        int br = t3 >> 9, t = t3 & 511;
        const float* xs = (br == 0) ? x1 : ((br == 1) ? x2 : x3);
        src = xs + ((size_t)b * TSEQ + t) * DD;
        dst = hq + (size_t)row * DD;
        sb = br * 4 + b;
    } else {
        int idx = row - 6144;
        src = xf + (size_t)idx * DD;
        dst = hx + (size_t)idx * DD;
        sb = 12 + (idx >> 9);
    }
    float4 x = ((const float4*)src)[tid];
    float s = x.x + x.y + x.z + x.w;
    float q = x.x * x.x + x.y * x.y + x.z * x.z + x.w * x.w;
    for (int o = 1; o < 64; o <<= 1) { s += __shfl_xor(s, o, 64); q += __shfl_xor(q, o, 64); }
    int lane = tid & 63, wid = tid >> 6;
    if (lane == 0) { rs[wid] = s; rq[wid] = q; }
    __syncthreads();
    float S = rs[0] + rs[1] + rs[2] + rs[3];
    float Q = rq[0] + rq[1] + rq[2] + rq[3];
    float mu = S * (1.f / DD);
    float var = Q * (1.f / DD) - mu * mu;
    float rstd = rsqrtf(var + 1e-6f);
    float4 sc = ((const float4*)(scaleB + (size_t)sb * DD))[tid];
    float4 sh = ((const float4*)(shiftB + (size_t)sb * DD))[tid];
    ushort4 o;
    o.x = f2bf((x.x - mu) * rstd * (1.f + sc.x) + sh.x);
    o.y = f2bf((x.y - mu) * rstd * (1.f + sc.y) + sh.y);
    o.z = f2bf((x.z - mu) * rstd * (1.f + sc.z) + sh.z);
    o.w = f2bf((x.w - mu) * rstd * (1.f + sc.w) + sh.w);
    ((ushort4*)dst)[tid] = o;
}

// ---------------------------------------------------------------------------
// K3: fp32 -> bf16 bulk convert (weights). 2048 elems/block.
// ---------------------------------------------------------------------------
__global__ __launch_bounds__(256) void cvt_kernel(
    const float* __restrict__ in, unsigned short* __restrict__ out)
{
    size_t gid = (size_t)blockIdx.x * 256 + threadIdx.x;
    const float4* p = (const float4*)in;
    float4 a = p[gid * 2], b = p[gid * 2 + 1];
    uint4 u;
    u.x = (uint32_t)f2bf(a.x) | ((uint32_t)f2bf(a.y) << 16);
    u.y = (uint32_t)f2bf(a.z) | ((uint32_t)f2bf(a.w) << 16);
    u.z = (uint32_t)f2bf(b.x) | ((uint32_t)f2bf(b.y) << 16);
    u.w = (uint32_t)f2bf(b.z) | ((uint32_t)f2bf(b.w) << 16);
    ((uint4*)out)[gid] = u;
}

// ---------------------------------------------------------------------------
// K4: bf16 MFMA GEMM, 64x64 tile, BK=32, 256 thr (4 waves 2x2 of 32x32).
// MODE 0: Q proj (branch W, bf16 out row-major)
// MODE 1: K proj (bf16 out row-major)
// MODE 2: V proj (bf16 out scattered to VT[b,h,hd,n])
// MODE 3: out proj (branch W, fp32 out remapped branch-major)
// ---------------------------------------------------------------------------
template <int MODE>
__global__ __launch_bounds__(256) void gemm_kernel(
    const unsigned short* __restrict__ A,
    const unsigned short* __restrict__ W,
    const float* __restrict__ bias,
    void* __restrict__ outp)
{
    int n0 = blockIdx.x * 64;
    int m0 = blockIdx.y * 64;
    int branch = (MODE == 0 || MODE == 3) ? ((m0 % 1536) >> 9) : 0;
    const unsigned short* Wp = W + (size_t)branch * DD * DD;
    const float* bp = bias + (size_t)branch * DD;
    __shared__ __align__(16) unsigned short As[64 * 32];
    __shared__ __align__(16) unsigned short Ws[64 * 32];  // transposed [n][k]
    int tid = threadIdx.x, lane = tid & 63, wid = tid >> 6;
    int wm = wid >> 1, wn = wid & 1;
    int fm = lane & 15, quad = lane >> 4;
    f32x4 z = {0.f, 0.f, 0.f, 0.f};
    f32x4 acc[2][2];
    acc[0][0] = z; acc[0][1] = z; acc[1][0] = z; acc[1][1] = z;
    int ar = tid >> 2, ako = (tid & 3) * 8;
    int wkr = tid >> 3, wnc = (tid & 7) * 8;
    for (int k0 = 0; k0 < DD; k0 += 32) {
        uint4 av = *(const uint4*)(A + (size_t)(m0 + ar) * DD + k0 + ako);
        uint4 wv = *(const uint4*)(Wp + (size_t)(k0 + wkr) * DD + n0 + wnc);
        *(uint4*)(As + ar * 32 + ako) = av;
        const unsigned short* pw = (const unsigned short*)&wv;
#pragma unroll
        for (int jj = 0; jj < 8; jj++) Ws[(wnc + jj) * 32 + wkr] = pw[jj];
        __syncthreads();
        bf16x8 af0 = *(const bf16x8*)(As + (wm * 32 + fm) * 32 + quad * 8);
        bf16x8 af1 = *(const bf16x8*)(As + (wm * 32 + 16 + fm) * 32 + quad * 8);
        bf16x8 bg0 = *(const bf16x8*)(Ws + (wn * 32 + fm) * 32 + quad * 8);
        bf16x8 bg1 = *(const bf16x8*)(Ws + (wn * 32 + 16 + fm) * 32 + quad * 8);
        acc[0][0] = __builtin_amdgcn_mfma_f32_16x16x32_bf16(af0, bg0, acc[0][0], 0, 0, 0);
        acc[0][1] = __builtin_amdgcn_mfma_f32_16x16x32_bf16(af0, bg1, acc[0][1], 0, 0, 0);
        acc[1][0] = __builtin_amdgcn_mfma_f32_16x16x32_bf16(af1, bg0, acc[1][0], 0, 0, 0);
        acc[1][1] = __builtin_amdgcn_mfma_f32_16x16x32_bf16(af1, bg1, acc[1][1], 0, 0, 0);
        __syncthreads();
    }
#pragma unroll
    for (int mt = 0; mt < 2; mt++) {
#pragma unroll
        for (int nt = 0; nt < 2; nt++) {
            int c = n0 + wn * 32 + nt * 16 + fm;
            float bv = bp[c];
#pragma unroll
            for (int reg = 0; reg < 4; reg++) {
                int r = m0 + wm * 32 + mt * 16 + quad * 4 + reg;
                float v = acc[mt][nt][reg] + bv;
                if (MODE == 0 || MODE == 1) {
                    ((unsigned short*)outp)[(size_t)r * DD + c] = f2bf(v);
                } else if (MODE == 2) {
                    int b = r >> 9, n = r & 511, h = c >> 6, hd = c & 63;
                    ((unsigned short*)outp)[(((size_t)(b * HH + h)) * HD + hd) * NSEQ + n] = f2bf(v);
                } else {
                    int b = r / 1536, t3 = r % 1536, br = t3 >> 9, t = t3 & 511;
                    ((float*)outp)[(size_t)br * (BB * TSEQ * DD) + (size_t)b * (TSEQ * DD)
                                   + (size_t)t * DD + c] = v;
                }
            }
        }
    }
}

// ---------------------------------------------------------------------------
// K5: attention. grid (96 q-tiles of 16, B*H). block 256 (4 waves).
// S = Q K^T /8 -> softmax -> O = P V, P staged bf16 in LDS, V read as VT.
// ---------------------------------------------------------------------------
__global__ __launch_bounds__(256) void attn_kernel(
    const unsigned short* __restrict__ Qb,
    const unsigned short* __restrict__ Kb,
    const unsigned short* __restrict__ VT,
    const unsigned char* __restrict__ mask,
    unsigned short* __restrict__ attn)
{
    __shared__ __align__(16) float S[16 * 516];           // padded stride
    __shared__ __align__(16) unsigned short P[16 * 520];  // padded stride
    __shared__ float rowinv[16];
    int bh = blockIdx.y;
    int b = bh >> 4, h = bh & 15;
    int m0 = blockIdx.x * 16;
    int tid = threadIdx.x, lane = tid & 63, wid = tid >> 6;
    int fm = lane & 15, quad = lane >> 4;
    // phase 1: S = Q K^T  (wave wid covers key cols [wid*128, wid*128+128))
    {
        f32x4 z = {0.f, 0.f, 0.f, 0.f};
        f32x4 acc[8];
#pragma unroll
        for (int i = 0; i < 8; i++) acc[i] = z;
        const unsigned short* Qp = Qb + ((size_t)b * 1536 + m0) * DD + h * HD;
        const unsigned short* Kp = Kb + ((size_t)b * NSEQ) * DD + h * HD;
#pragma unroll
        for (int kk = 0; kk < 2; kk++) {
            bf16x8 aq = *(const bf16x8*)(Qp + (size_t)fm * DD + kk * 32 + quad * 8);
#pragma unroll
            for (int nt = 0; nt < 8; nt++) {
                bf16x8 bk = *(const bf16x8*)(Kp + (size_t)(wid * 128 + nt * 16 + fm) * DD
                                             + kk * 32 + quad * 8);
                acc[nt] = __builtin_amdgcn_mfma_f32_16x16x32_bf16(aq, bk, acc[nt], 0, 0, 0);
            }
        }
#pragma unroll
        for (int nt = 0; nt < 8; nt++)
#pragma unroll
            for (int reg = 0; reg < 4; reg++)
                S[(quad * 4 + reg) * 516 + wid * 128 + nt * 16 + fm] = acc[nt][reg];
    }
    __syncthreads();
    // phase 2: softmax over 512 keys; 16 threads per row, strided columns
    {
        int r = tid >> 4, g = tid & 15;
        const unsigned char* mp = mask + (size_t)b * NSEQ;
        float vals[32];
        float mx = -1e30f;
#pragma unroll 8
        for (int i = 0; i < 32; i++) {
            int n = i * 16 + g;
            float sv = S[r * 516 + n] * 0.125f;
            if (mp[n]) sv = -1e30f;
            vals[i] = sv;
            mx = fmaxf(mx, sv);
        }
#pragma unroll
        for (int o = 1; o < 16; o <<= 1) mx = fmaxf(mx, __shfl_xor(mx, o, 64));
        float sum = 0.f;
#pragma unroll 8
        for (int i = 0; i < 32; i++) {
            float e = __expf(vals[i] - mx);
            sum += e;
            P[r * 520 + i * 16 + g] = f2bf(e);
        }
#pragma unroll
        for (int o = 1; o < 16; o <<= 1) sum += __shfl_xor(sum, o, 64);
        if (g == 0) rowinv[r] = 1.f / sum;
    }
    __syncthreads();
    // phase 3: O = P @ V^T ; wave wid computes hd-tile [wid*16, wid*16+16)
    {
        f32x4 acc = {0.f, 0.f, 0.f, 0.f};
        const unsigned short* Vp = VT + ((size_t)bh * HD + wid * 16 + fm) * NSEQ;
        const unsigned short* Pp = P + (size_t)fm * 520;
#pragma unroll
        for (int kk = 0; kk < 16; kk++) {
            bf16x8 ap = *(const bf16x8*)(Pp + kk * 32 + quad * 8);
            bf16x8 bv = *(const bf16x8*)(Vp + kk * 32 + quad * 8);
            acc = __builtin_amdgcn_mfma_f32_16x16x32_bf16(ap, bv, acc, 0, 0, 0);
        }
        int c = h * HD + wid * 16 + fm;
#pragma unroll
        for (int reg = 0; reg < 4; reg++) {
            int rl = quad * 4 + reg;
            float o = acc[reg] * rowinv[rl];
            attn[((size_t)b * 1536 + m0 + rl) * DD + c] = f2bf(o);
        }
    }
}

// ---------------------------------------------------------------------------
extern "C" void kernel_launch(void* const* d_in, const int* in_sizes, int n_in,
                              void* d_out, int out_size, void* d_ws, size_t ws_size,
                              hipStream_t stream)
{
    const float* x1   = (const float*)d_in[0];
    const float* x2   = (const float*)d_in[1];
    const float* x3   = (const float*)d_in[2];
    const float* xf   = (const float*)d_in[3];
    const float* emb  = (const float*)d_in[4];
    const unsigned char* mask = (const unsigned char*)d_in[5];
    const float* adaln_w = (const float*)d_in[6];
    const float* adaln_b = (const float*)d_in[7];
    const float* xf_w = (const float*)d_in[8];
    const float* xf_b = (const float*)d_in[9];
    const float* q_w  = (const float*)d_in[10];
    const float* q_b  = (const float*)d_in[11];
    const float* k_w  = (const float*)d_in[12];
    const float* k_b  = (const float*)d_in[13];
    const float* v_w  = (const float*)d_in[14];
    const float* v_b  = (const float*)d_in[15];
    const float* out_w = (const float*)d_in[16];
    const float* out_b = (const float*)d_in[17];

    char* ws = (char*)d_ws;
    float* scaleB        = (float*)(ws + 0);
    float* shiftB        = (float*)(ws + 65536);
    unsigned short* hq   = (unsigned short*)(ws + 131072);     // 12.58 MB, reused as attn out
    unsigned short* hx   = (unsigned short*)(ws + 12713984);   // 4.19 MB
    unsigned short* Qb   = (unsigned short*)(ws + 16908288);   // 12.58 MB
    unsigned short* Kb   = (unsigned short*)(ws + 29491200);   // 4.19 MB
    unsigned short* VT   = (unsigned short*)(ws + 33685504);   // 4.19 MB
    unsigned short* qwb  = (unsigned short*)(ws + 37879808);   // 6.29 MB
    unsigned short* kwb  = (unsigned short*)(ws + 44171264);   // 2.10 MB
    unsigned short* vwb  = (unsigned short*)(ws + 46268416);   // 2.10 MB
    unsigned short* owb  = (unsigned short*)(ws + 48365568);   // 6.29 MB  (end ~54.7 MB)

    adaln_kernel<<<dim3(8, 4, 4), 256, 0, stream>>>(emb, adaln_w, adaln_b, xf_w, xf_b,
                                                    scaleB, shiftB);
    ln_mod_kernel<<<8192, 256, 0, stream>>>(x1, x2, x3, xf, scaleB, shiftB, hq, hx);
    cvt_kernel<<<1536, 256, 0, stream>>>(q_w, qwb);
    cvt_kernel<<<512, 256, 0, stream>>>(k_w, kwb);
    cvt_kernel<<<512, 256, 0, stream>>>(v_w, vwb);
    cvt_kernel<<<1536, 256, 0, stream>>>(out_w, owb);
    gemm_kernel<0><<<dim3(16, 96), 256, 0, stream>>>(hq, qwb, q_b, (void*)Qb);
    gemm_kernel<1><<<dim3(16, 32), 256, 0, stream>>>(hx, kwb, k_b, (void*)Kb);
    gemm_kernel<2><<<dim3(16, 32), 256, 0, stream>>>(hx, vwb, v_b, (void*)VT);
    attn_kernel<<<dim3(96, 64), 256, 0, stream>>>(Qb, Kb, VT, mask, hq);
    gemm_kernel<3><<<dim3(16, 96), 256, 0, stream>>>(hq, owb, out_b, d_out);
}

// Round 2
// 365.470 us; speedup vs baseline: 1.4929x; 1.4929x over previous
//
#include <hip/hip_runtime.h>
#include <stdint.h>

#define BB 4
#define TSEQ 512
#define NSEQ 512
#define DD 1024
#define EE 1024
#define HH 16
#define HD 64

typedef __attribute__((ext_vector_type(8))) short bf16x8;
typedef __attribute__((ext_vector_type(4))) float f32x4;

__device__ __forceinline__ unsigned short f2bf(float f) {
    union { float f; uint32_t u; } v; v.f = f;
    uint32_t u = v.u;
    uint32_t r = (u + 0x7fffu + ((u >> 16) & 1u)) >> 16;
    return (unsigned short)r;
}

#define GLD16(gp, lp)                                                          \
    __builtin_amdgcn_global_load_lds(                                          \
        (const __attribute__((address_space(1))) unsigned int*)(gp),           \
        (__attribute__((address_space(3))) unsigned int*)(lp), 16, 0, 0)

// ---------------------------------------------------------------------------
// K1: se = silu(emb); eo = se @ W_j + b_j ; split into scale/shift
// ---------------------------------------------------------------------------
__global__ __launch_bounds__(256) void adaln_kernel(
    const float* __restrict__ emb,
    const float* __restrict__ adaln_w, const float* __restrict__ adaln_b,
    const float* __restrict__ xf_w, const float* __restrict__ xf_b,
    float* __restrict__ scaleB, float* __restrict__ shiftB)
{
    __shared__ float se[EE];
    int tid = threadIdx.x;
    int chunk = blockIdx.x, b = blockIdx.y, j = blockIdx.z;
    float4 e4 = ((const float4*)(emb + (size_t)b * EE))[tid];
    se[tid * 4 + 0] = e4.x / (1.f + __expf(-e4.x));
    se[tid * 4 + 1] = e4.y / (1.f + __expf(-e4.y));
    se[tid * 4 + 2] = e4.z / (1.f + __expf(-e4.z));
    se[tid * 4 + 3] = e4.w / (1.f + __expf(-e4.w));
    __syncthreads();
    const float* W    = (j < 3) ? (adaln_w + (size_t)j * EE * 2 * DD) : xf_w;
    const float* bias = (j < 3) ? (adaln_b + (size_t)j * 2 * DD) : xf_b;
    int c = chunk * 256 + tid;
    float acc = 0.f;
#pragma unroll 8
    for (int e = 0; e < EE; e++) acc += se[e] * W[(size_t)e * (2 * DD) + c];
    float v = acc + bias[c];
    if (c < DD) scaleB[(size_t)(j * 4 + b) * DD + c] = v;
    else        shiftB[(size_t)(j * 4 + b) * DD + (c - DD)] = v;
}

// ---------------------------------------------------------------------------
// K2: LayerNorm + modulate, cast bf16
// ---------------------------------------------------------------------------
__global__ __launch_bounds__(256) void ln_mod_kernel(
    const float* __restrict__ x1, const float* __restrict__ x2,
    const float* __restrict__ x3, const float* __restrict__ xf,
    const float* __restrict__ scaleB, const float* __restrict__ shiftB,
    unsigned short* __restrict__ hq, unsigned short* __restrict__ hx)
{
    __shared__ float rs[4], rq[4];
    int row = blockIdx.x, tid = threadIdx.x;
    const float* src; unsigned short* dst; int sb;
    if (row < 6144) {
        int b = row / 1536, t3 = row % 1536;
        int br = t3 >> 9, t = t3 & 511;
        const float* xs = (br == 0) ? x1 : ((br == 1) ? x2 : x3);
        src = xs + ((size_t)b * TSEQ + t) * DD;
        dst = hq + (size_t)row * DD;
        sb = br * 4 + b;
    } else {
        int idx = row - 6144;
        src = xf + (size_t)idx * DD;
        dst = hx + (size_t)idx * DD;
        sb = 12 + (idx >> 9);
    }
    float4 x = ((const float4*)src)[tid];
    float s = x.x + x.y + x.z + x.w;
    float q = x.x * x.x + x.y * x.y + x.z * x.z + x.w * x.w;
    for (int o = 1; o < 64; o <<= 1) { s += __shfl_xor(s, o, 64); q += __shfl_xor(q, o, 64); }
    int lane = tid & 63, wid = tid >> 6;
    if (lane == 0) { rs[wid] = s; rq[wid] = q; }
    __syncthreads();
    float S = rs[0] + rs[1] + rs[2] + rs[3];
    float Q = rq[0] + rq[1] + rq[2] + rq[3];
    float mu = S * (1.f / DD);
    float var = Q * (1.f / DD) - mu * mu;
    float rstd = rsqrtf(var + 1e-6f);
    float4 sc = ((const float4*)(scaleB + (size_t)sb * DD))[tid];
    float4 sh = ((const float4*)(shiftB + (size_t)sb * DD))[tid];
    ushort4 o;
    o.x = f2bf((x.x - mu) * rstd * (1.f + sc.x) + sh.x);
    o.y = f2bf((x.y - mu) * rstd * (1.f + sc.y) + sh.y);
    o.z = f2bf((x.z - mu) * rstd * (1.f + sc.z) + sh.z);
    o.w = f2bf((x.w - mu) * rstd * (1.f + sc.w) + sh.w);
    ((ushort4*)dst)[tid] = o;
}

// ---------------------------------------------------------------------------
// K3: weight transpose + cvt: W[k][n] fp32 -> WT[n][k] bf16. 64x64 tiles.
// grid (16 ktiles, 16 ntiles, nbranch)
// ---------------------------------------------------------------------------
__global__ __launch_bounds__(256) void tw_kernel(
    const float* __restrict__ in, unsigned short* __restrict__ out)
{
    __shared__ __align__(16) unsigned short Ts[64 * 72];
    int k0 = blockIdx.x * 64, n0 = blockIdx.y * 64;
    size_t base = (size_t)blockIdx.z * (DD * DD);
    int tid = threadIdx.x;
    int r = tid >> 2, c0 = (tid & 3) * 16;
#pragma unroll
    for (int i = 0; i < 4; i++) {
        float4 v = *(const float4*)(in + base + (size_t)(k0 + r) * DD + n0 + c0 + i * 4);
        Ts[(c0 + i * 4 + 0) * 72 + r] = f2bf(v.x);
        Ts[(c0 + i * 4 + 1) * 72 + r] = f2bf(v.y);
        Ts[(c0 + i * 4 + 2) * 72 + r] = f2bf(v.z);
        Ts[(c0 + i * 4 + 3) * 72 + r] = f2bf(v.w);
    }
    __syncthreads();
#pragma unroll
    for (int i = 0; i < 2; i++) {
        int idx = i * 256 + tid;
        int row = idx >> 3, ko = (idx & 7) * 8;
        *(uint4*)(out + base + (size_t)(n0 + row) * DD + k0 + ko) =
            *(const uint4*)(Ts + row * 72 + ko);
    }
}

// ---------------------------------------------------------------------------
// GEMM core: 128x128 tile, BK=32, global_load_lds staging, 4 waves 2x2 of 64x64
// A [M][1024] bf16, W [N][1024] bf16 (pre-transposed)
// ---------------------------------------------------------------------------
__device__ __forceinline__ void gemm_core(
    const unsigned short* __restrict__ A, const unsigned short* __restrict__ W,
    int m0, int n0, unsigned short* As, unsigned short* Bs,
    int tid, f32x4 acc[4][4])
{
    int lane = tid & 63, wid = tid >> 6;
    int fm = lane & 15, quad = lane >> 4;
    int wm = wid >> 1, wn = wid & 1;
    int r0 = tid >> 2, ko = (tid & 3) * 8;
    const unsigned short* Ap0 = A + (size_t)(m0 + r0) * DD + ko;
    const unsigned short* Ap1 = A + (size_t)(m0 + r0 + 64) * DD + ko;
    const unsigned short* Wp0 = W + (size_t)(n0 + r0) * DD + ko;
    const unsigned short* Wp1 = W + (size_t)(n0 + r0 + 64) * DD + ko;
    unsigned short* la0 = As + tid * 8;
    unsigned short* la1 = As + (256 + tid) * 8;
    unsigned short* lb0 = Bs + tid * 8;
    unsigned short* lb1 = Bs + (256 + tid) * 8;
    for (int k0 = 0; k0 < DD; k0 += 32) {
        GLD16(Ap0 + k0, la0);
        GLD16(Ap1 + k0, la1);
        GLD16(Wp0 + k0, lb0);
        GLD16(Wp1 + k0, lb1);
        __syncthreads();
        bf16x8 af[4], bf[4];
#pragma unroll
        for (int mt = 0; mt < 4; mt++)
            af[mt] = *(const bf16x8*)(As + (wm * 64 + mt * 16 + fm) * 32 + quad * 8);
#pragma unroll
        for (int nt = 0; nt < 4; nt++)
            bf[nt] = *(const bf16x8*)(Bs + (wn * 64 + nt * 16 + fm) * 32 + quad * 8);
#pragma unroll
        for (int mt = 0; mt < 4; mt++)
#pragma unroll
            for (int nt = 0; nt < 4; nt++)
                acc[mt][nt] = __builtin_amdgcn_mfma_f32_16x16x32_bf16(af[mt], bf[nt], acc[mt][nt], 0, 0, 0);
        __syncthreads();
    }
}

// ---------------------------------------------------------------------------
// K4: fused Q/K/V projection. grid (8, 80): y<48 Q, y<64 K, else V.
// ---------------------------------------------------------------------------
__global__ __launch_bounds__(256) void qkv_gemm(
    const unsigned short* __restrict__ hq, const unsigned short* __restrict__ hx,
    const unsigned short* __restrict__ qwt, const unsigned short* __restrict__ kwt,
    const unsigned short* __restrict__ vwt,
    const float* __restrict__ q_b, const float* __restrict__ k_b,
    const float* __restrict__ v_b,
    unsigned short* __restrict__ Qb, unsigned short* __restrict__ Kb,
    unsigned short* __restrict__ VT)
{
    __shared__ __align__(16) unsigned short As[128 * 32];
    __shared__ __align__(16) unsigned short Bs[128 * 32];
    int ty = blockIdx.y, n0 = blockIdx.x * 128;
    const unsigned short *A, *W; const float* bias; int mode, m0;
    if (ty < 48) {
        m0 = ty * 128;
        int br = (m0 % 1536) >> 9;
        A = hq; W = qwt + (size_t)br * DD * DD; bias = q_b + (size_t)br * DD; mode = 0;
    } else if (ty < 64) {
        m0 = (ty - 48) * 128; A = hx; W = kwt; bias = k_b; mode = 1;
    } else {
        m0 = (ty - 64) * 128; A = hx; W = vwt; bias = v_b; mode = 2;
    }
    int tid = threadIdx.x, lane = tid & 63, wid = tid >> 6;
    int fm = lane & 15, quad = lane >> 4;
    int wm = wid >> 1, wn = wid & 1;
    f32x4 z = {0.f, 0.f, 0.f, 0.f};
    f32x4 acc[4][4];
#pragma unroll
    for (int mt = 0; mt < 4; mt++)
#pragma unroll
        for (int nt = 0; nt < 4; nt++) acc[mt][nt] = z;
    gemm_core(A, W, m0, n0, As, Bs, tid, acc);
#pragma unroll
    for (int mt = 0; mt < 4; mt++) {
#pragma unroll
        for (int nt = 0; nt < 4; nt++) {
            int c = n0 + wn * 64 + nt * 16 + fm;
            float bv = bias[c];
            int r0 = m0 + wm * 64 + mt * 16 + quad * 4;
            if (mode == 2) {
                int b = r0 >> 9, n = r0 & 511, hh = c >> 6, hd = c & 63;
                ushort4 st;
                st.x = f2bf(acc[mt][nt][0] + bv);
                st.y = f2bf(acc[mt][nt][1] + bv);
                st.z = f2bf(acc[mt][nt][2] + bv);
                st.w = f2bf(acc[mt][nt][3] + bv);
                *(ushort4*)(VT + (((size_t)(b * HH + hh)) * HD + hd) * NSEQ + n) = st;
            } else {
                unsigned short* dst = (mode == 0) ? Qb : Kb;
#pragma unroll
                for (int reg = 0; reg < 4; reg++)
                    dst[(size_t)(r0 + reg) * DD + c] = f2bf(acc[mt][nt][reg] + bv);
            }
        }
    }
}

// ---------------------------------------------------------------------------
// K6: out projection, fp32 out remapped branch-major. grid (8, 48)
// ---------------------------------------------------------------------------
__global__ __launch_bounds__(256) void out_gemm(
    const unsigned short* __restrict__ Ain, const unsigned short* __restrict__ owt,
    const float* __restrict__ out_b, float* __restrict__ outp)
{
    __shared__ __align__(16) unsigned short As[128 * 32];
    __shared__ __align__(16) unsigned short Bs[128 * 32];
    int n0 = blockIdx.x * 128, m0 = blockIdx.y * 128;
    int br = (m0 % 1536) >> 9;
    const unsigned short* W = owt + (size_t)br * DD * DD;
    const float* bias = out_b + (size_t)br * DD;
    int tid = threadIdx.x, lane = tid & 63, wid = tid >> 6;
    int fm = lane & 15, quad = lane >> 4;
    int wm = wid >> 1, wn = wid & 1;
    f32x4 z = {0.f, 0.f, 0.f, 0.f};
    f32x4 acc[4][4];
#pragma unroll
    for (int mt = 0; mt < 4; mt++)
#pragma unroll
        for (int nt = 0; nt < 4; nt++) acc[mt][nt] = z;
    gemm_core(Ain, W, m0, n0, As, Bs, tid, acc);
#pragma unroll
    for (int mt = 0; mt < 4; mt++) {
#pragma unroll
        for (int nt = 0; nt < 4; nt++) {
            int c = n0 + wn * 64 + nt * 16 + fm;
            float bv = bias[c];
            int r0 = m0 + wm * 64 + mt * 16 + quad * 4;
            int b = r0 / 1536, t3 = r0 % 1536, t = t3 & 511;
#pragma unroll
            for (int reg = 0; reg < 4; reg++)
                outp[(size_t)br * (BB * TSEQ * DD) + (size_t)b * (TSEQ * DD)
                     + (size_t)(t + reg) * DD + c] = acc[mt][nt][reg] + bv;
        }
    }
}

// ---------------------------------------------------------------------------
// K5: attention, 32 queries/block, S^T in registers. grid (48, 64)
// phase1: S^T = K Q^T (lane holds 4 consecutive keys/reg)
// phase2: register softmax (shuffle across quads, LDS across waves), P -> LDS b64
// phase3: O^T = V^T P via ds_read_b128 B-frags, ushort4 stores
// ---------------------------------------------------------------------------
__global__ __launch_bounds__(256) void attn_kernel(
    const unsigned short* __restrict__ Qb,
    const unsigned short* __restrict__ Kb,
    const unsigned short* __restrict__ VT,
    const unsigned char* __restrict__ mask,
    unsigned short* __restrict__ attn)
{
    __shared__ __align__(16) unsigned short P[32 * 520];
    __shared__ unsigned long long maskb[8];
    __shared__ float redmax[128];
    __shared__ float redsum[128];
    int bh = blockIdx.y, b = bh >> 4, h = bh & 15;
    int m0 = blockIdx.x * 32;
    int tid = threadIdx.x, lane = tid & 63, w = tid >> 6;
    int fm = lane & 15, quad = lane >> 4;

    {
        const unsigned char* mp = mask + (size_t)b * NSEQ;
        unsigned long long lo = __ballot(mp[w * 64 + lane] != 0);
        unsigned long long hi = __ballot(mp[256 + w * 64 + lane] != 0);
        if (lane == 0) { maskb[w] = lo; maskb[4 + w] = hi; }
    }
    __syncthreads();

    // phase 1
    f32x4 z = {0.f, 0.f, 0.f, 0.f};
    f32x4 acc[8][2];
#pragma unroll
    for (int mt = 0; mt < 8; mt++) { acc[mt][0] = z; acc[mt][1] = z; }
    const unsigned short* Kp = Kb + ((size_t)(b * NSEQ + w * 128 + fm)) * DD + h * HD + quad * 8;
    const unsigned short* Qp = Qb + ((size_t)(b * 1536 + m0 + fm)) * DD + h * HD + quad * 8;
#pragma unroll
    for (int kk = 0; kk < 2; kk++) {
        bf16x8 bq0 = *(const bf16x8*)(Qp + kk * 32);
        bf16x8 bq1 = *(const bf16x8*)(Qp + (size_t)16 * DD + kk * 32);
#pragma unroll
        for (int mt = 0; mt < 8; mt++) {
            bf16x8 ak = *(const bf16x8*)(Kp + (size_t)mt * 16 * DD + kk * 32);
            acc[mt][0] = __builtin_amdgcn_mfma_f32_16x16x32_bf16(ak, bq0, acc[mt][0], 0, 0, 0);
            acc[mt][1] = __builtin_amdgcn_mfma_f32_16x16x32_bf16(ak, bq1, acc[mt][1], 0, 0, 0);
        }
    }

    // phase 2: scale + mask + column (query) max
    unsigned long long mw0 = maskb[w * 2], mw1 = maskb[w * 2 + 1];
    float cmax0 = -1e30f, cmax1 = -1e30f;
#pragma unroll
    for (int mt = 0; mt < 8; mt++) {
        unsigned long long word = (mt >= 4) ? mw1 : mw0;
        int kb = (w * 128 + mt * 16 + quad * 4) & 63;
#pragma unroll
        for (int reg = 0; reg < 4; reg++) {
            bool msk = (word >> (kb + reg)) & 1ull;
            float v0 = acc[mt][0][reg] * 0.125f;
            float v1 = acc[mt][1][reg] * 0.125f;
            v0 = msk ? -1e30f : v0;
            v1 = msk ? -1e30f : v1;
            acc[mt][0][reg] = v0; acc[mt][1][reg] = v1;
            cmax0 = fmaxf(cmax0, v0); cmax1 = fmaxf(cmax1, v1);
        }
    }
    cmax0 = fmaxf(cmax0, __shfl_xor(cmax0, 16, 64));
    cmax0 = fmaxf(cmax0, __shfl_xor(cmax0, 32, 64));
    cmax1 = fmaxf(cmax1, __shfl_xor(cmax1, 16, 64));
    cmax1 = fmaxf(cmax1, __shfl_xor(cmax1, 32, 64));
    if (quad == 0) { redmax[w * 32 + fm] = cmax0; redmax[w * 32 + 16 + fm] = cmax1; }
    __syncthreads();
    float g0 = fmaxf(fmaxf(redmax[fm], redmax[32 + fm]),
                     fmaxf(redmax[64 + fm], redmax[96 + fm]));
    float g1 = fmaxf(fmaxf(redmax[16 + fm], redmax[48 + fm]),
                     fmaxf(redmax[80 + fm], redmax[112 + fm]));
    float s0 = 0.f, s1 = 0.f;
#pragma unroll
    for (int mt = 0; mt < 8; mt++) {
        float e00 = __expf(acc[mt][0][0] - g0);
        float e01 = __expf(acc[mt][0][1] - g0);
        float e02 = __expf(acc[mt][0][2] - g0);
        float e03 = __expf(acc[mt][0][3] - g0);
        float e10 = __expf(acc[mt][1][0] - g1);
        float e11 = __expf(acc[mt][1][1] - g1);
        float e12 = __expf(acc[mt][1][2] - g1);
        float e13 = __expf(acc[mt][1][3] - g1);
        s0 += (e00 + e01) + (e02 + e03);
        s1 += (e10 + e11) + (e12 + e13);
        ushort4 p0, p1;
        p0.x = f2bf(e00); p0.y = f2bf(e01); p0.z = f2bf(e02); p0.w = f2bf(e03);
        p1.x = f2bf(e10); p1.y = f2bf(e11); p1.z = f2bf(e12); p1.w = f2bf(e13);
        int kb = w * 128 + mt * 16 + quad * 4;
        *(ushort4*)(P + (size_t)fm * 520 + kb) = p0;
        *(ushort4*)(P + (size_t)(16 + fm) * 520 + kb) = p1;
    }
    s0 += __shfl_xor(s0, 16, 64); s0 += __shfl_xor(s0, 32, 64);
    s1 += __shfl_xor(s1, 16, 64); s1 += __shfl_xor(s1, 32, 64);
    if (quad == 0) { redsum[w * 32 + fm] = s0; redsum[w * 32 + 16 + fm] = s1; }
    __syncthreads();

    // phase 3
    float inv0 = 1.f / (redsum[fm] + redsum[32 + fm] + redsum[64 + fm] + redsum[96 + fm]);
    float inv1 = 1.f / (redsum[16 + fm] + redsum[48 + fm] + redsum[80 + fm] + redsum[112 + fm]);
    f32x4 o0 = z, o1 = z;
    const unsigned short* Vp = VT + ((size_t)(bh * HD + w * 16 + fm)) * NSEQ + quad * 8;
    const unsigned short* Pp0 = P + (size_t)fm * 520 + quad * 8;
    const unsigned short* Pp1 = P + (size_t)(16 + fm) * 520 + quad * 8;
#pragma unroll
    for (int kk = 0; kk < 16; kk++) {
        bf16x8 av = *(const bf16x8*)(Vp + kk * 32);
        bf16x8 p0 = *(const bf16x8*)(Pp0 + kk * 32);
        bf16x8 p1 = *(const bf16x8*)(Pp1 + kk * 32);
        o0 = __builtin_amdgcn_mfma_f32_16x16x32_bf16(av, p0, o0, 0, 0, 0);
        o1 = __builtin_amdgcn_mfma_f32_16x16x32_bf16(av, p1, o1, 0, 0, 0);
    }
    ushort4 r0, r1;
    r0.x = f2bf(o0[0] * inv0); r0.y = f2bf(o0[1] * inv0);
    r0.z = f2bf(o0[2] * inv0); r0.w = f2bf(o0[3] * inv0);
    r1.x = f2bf(o1[0] * inv1); r1.y = f2bf(o1[1] * inv1);
    r1.z = f2bf(o1[2] * inv1); r1.w = f2bf(o1[3] * inv1);
    *(ushort4*)(attn + ((size_t)(b * 1536 + m0 + fm)) * DD + h * HD + w * 16 + quad * 4) = r0;
    *(ushort4*)(attn + ((size_t)(b * 1536 + m0 + 16 + fm)) * DD + h * HD + w * 16 + quad * 4) = r1;
}

// ---------------------------------------------------------------------------
extern "C" void kernel_launch(void* const* d_in, const int* in_sizes, int n_in,
                              void* d_out, int out_size, void* d_ws, size_t ws_size,
                              hipStream_t stream)
{
    const float* x1   = (const float*)d_in[0];
    const float* x2   = (const float*)d_in[1];
    const float* x3   = (const float*)d_in[2];
    const float* xf   = (const float*)d_in[3];
    const float* emb  = (const float*)d_in[4];
    const unsigned char* mask = (const unsigned char*)d_in[5];
    const float* adaln_w = (const float*)d_in[6];
    const float* adaln_b = (const float*)d_in[7];
    const float* xf_w = (const float*)d_in[8];
    const float* xf_b = (const float*)d_in[9];
    const float* q_w  = (const float*)d_in[10];
    const float* q_b  = (const float*)d_in[11];
    const float* k_w  = (const float*)d_in[12];
    const float* k_b  = (const float*)d_in[13];
    const float* v_w  = (const float*)d_in[14];
    const float* v_b  = (const float*)d_in[15];
    const float* out_w = (const float*)d_in[16];
    const float* out_b = (const float*)d_in[17];

    char* ws = (char*)d_ws;
    float* scaleB        = (float*)(ws + 0);
    float* shiftB        = (float*)(ws + 65536);
    unsigned short* hq   = (unsigned short*)(ws + 131072);     // 12.58 MB (reused for attn out)
    unsigned short* hx   = (unsigned short*)(ws + 12713984);   // 4.19 MB
    unsigned short* Qb   = (unsigned short*)(ws + 16908288);   // 12.58 MB
    unsigned short* Kb   = (unsigned short*)(ws + 29491200);   // 4.19 MB
    unsigned short* VT   = (unsigned short*)(ws + 33685504);   // 4.19 MB
    unsigned short* qwt  = (unsigned short*)(ws + 37879808);   // 6.29 MB
    unsigned short* kwt  = (unsigned short*)(ws + 44171264);   // 2.10 MB
    unsigned short* vwt  = (unsigned short*)(ws + 46268416);   // 2.10 MB
    unsigned short* owt  = (unsigned short*)(ws + 48365568);   // 6.29 MB (end ~54.7 MB)

    tw_kernel<<<dim3(16, 16, 3), 256, 0, stream>>>(q_w, qwt);
    tw_kernel<<<dim3(16, 16, 1), 256, 0, stream>>>(k_w, kwt);
    tw_kernel<<<dim3(16, 16, 1), 256, 0, stream>>>(v_w, vwt);
    tw_kernel<<<dim3(16, 16, 3), 256, 0, stream>>>(out_w, owt);
    adaln_kernel<<<dim3(8, 4, 4), 256, 0, stream>>>(emb, adaln_w, adaln_b, xf_w, xf_b,
                                                    scaleB, shiftB);
    ln_mod_kernel<<<8192, 256, 0, stream>>>(x1, x2, x3, xf, scaleB, shiftB, hq, hx);
    qkv_gemm<<<dim3(8, 80), 256, 0, stream>>>(hq, hx, qwt, kwt, vwt, q_b, k_b, v_b,
                                              Qb, Kb, VT);
    attn_kernel<<<dim3(48, 64), 256, 0, stream>>>(Qb, Kb, VT, mask, hq);
    out_gemm<<<dim3(8, 48), 256, 0, stream>>>(hq, owt, out_b, (float*)d_out);
}

// Round 3
// 294.284 us; speedup vs baseline: 1.8540x; 1.2419x over previous
//
#include <hip/hip_runtime.h>
#include <stdint.h>

#define BB 4
#define TSEQ 512
#define NSEQ 512
#define DD 1024
#define EE 1024
#define HH 16
#define HD 64

typedef __attribute__((ext_vector_type(8))) short bf16x8;
typedef __attribute__((ext_vector_type(4))) float f32x4;

__device__ __forceinline__ unsigned short f2bf(float f) {
    union { float f; uint32_t u; } v; v.f = f;
    uint32_t u = v.u;
    uint32_t r = (u + 0x7fffu + ((u >> 16) & 1u)) >> 16;
    return (unsigned short)r;
}

#define GLD16(gp, lp)                                                          \
    __builtin_amdgcn_global_load_lds(                                          \
        (const __attribute__((address_space(1))) unsigned int*)(gp),           \
        (__attribute__((address_space(3))) unsigned int*)(lp), 16, 0, 0)

// ---------------------------------------------------------------------------
// K1: adaln. grid (64 col-chunks of 32, 4 branches), block 256.
// Each block: 32 cols x 4 batches, reads W once. threads = 32 E-groups x 8 cgs.
// ---------------------------------------------------------------------------
__global__ __launch_bounds__(256) void adaln_kernel(
    const float* __restrict__ emb,
    const float* __restrict__ adaln_w, const float* __restrict__ adaln_b,
    const float* __restrict__ xf_w, const float* __restrict__ xf_b,
    float* __restrict__ scaleB, float* __restrict__ shiftB)
{
    __shared__ __align__(16) float seT[EE][4];   // 16 KB, [e][b]
    __shared__ float buf[128 * 33];              // 16.9 KB
    int tid = threadIdx.x;
    int chunk = blockIdx.x, j = blockIdx.y;
#pragma unroll
    for (int b = 0; b < 4; b++) {
        float4 e4 = ((const float4*)(emb + (size_t)b * EE))[tid];
        seT[tid * 4 + 0][b] = e4.x / (1.f + __expf(-e4.x));
        seT[tid * 4 + 1][b] = e4.y / (1.f + __expf(-e4.y));
        seT[tid * 4 + 2][b] = e4.z / (1.f + __expf(-e4.z));
        seT[tid * 4 + 3][b] = e4.w / (1.f + __expf(-e4.w));
    }
    __syncthreads();
    const float* W    = (j < 3) ? (adaln_w + (size_t)j * EE * 2 * DD) : xf_w;
    const float* bias = (j < 3) ? (adaln_b + (size_t)j * 2 * DD) : xf_b;
    int eg = tid >> 3;          // 32 groups of 32 e
    int cg = tid & 7;           // 8 groups of 4 cols
    int c0 = chunk * 32 + cg * 4;
    const float* Wp = W + (size_t)(eg * 32) * (2 * DD) + c0;
    float4 a0 = {0,0,0,0}, a1 = {0,0,0,0}, a2 = {0,0,0,0}, a3 = {0,0,0,0};
#pragma unroll 8
    for (int e = 0; e < 32; e++) {
        float4 w = *(const float4*)(Wp + (size_t)e * (2 * DD));
        float4 s = *(const float4*)&seT[eg * 32 + e][0];
        a0.x += s.x * w.x; a0.y += s.x * w.y; a0.z += s.x * w.z; a0.w += s.x * w.w;
        a1.x += s.y * w.x; a1.y += s.y * w.y; a1.z += s.y * w.z; a1.w += s.y * w.w;
        a2.x += s.z * w.x; a2.y += s.z * w.y; a2.z += s.z * w.z; a2.w += s.z * w.w;
        a3.x += s.w * w.x; a3.y += s.w * w.y; a3.z += s.w * w.z; a3.w += s.w * w.w;
    }
    float accs[4][4] = {{a0.x,a0.y,a0.z,a0.w},{a1.x,a1.y,a1.z,a1.w},
                        {a2.x,a2.y,a2.z,a2.w},{a3.x,a3.y,a3.z,a3.w}};
#pragma unroll
    for (int b = 0; b < 4; b++)
#pragma unroll
        for (int i = 0; i < 4; i++)
            buf[(b * 32 + cg * 4 + i) * 33 + eg] = accs[b][i];
    __syncthreads();
    if (tid < 128) {
        int b = tid >> 5, cl = tid & 31;
        float s = 0.f;
#pragma unroll 8
        for (int e = 0; e < 32; e++) s += buf[(b * 32 + cl) * 33 + e];
        int c = chunk * 32 + cl;
        float v = s + bias[c];
        if (c < DD) scaleB[(size_t)(j * 4 + b) * DD + c] = v;
        else        shiftB[(size_t)(j * 4 + b) * DD + (c - DD)] = v;
    }
}

// ---------------------------------------------------------------------------
// K2: LayerNorm + modulate, cast bf16
// ---------------------------------------------------------------------------
__global__ __launch_bounds__(256) void ln_mod_kernel(
    const float* __restrict__ x1, const float* __restrict__ x2,
    const float* __restrict__ x3, const float* __restrict__ xf,
    const float* __restrict__ scaleB, const float* __restrict__ shiftB,
    unsigned short* __restrict__ hq, unsigned short* __restrict__ hx)
{
    __shared__ float rs[4], rq[4];
    int row = blockIdx.x, tid = threadIdx.x;
    const float* src; unsigned short* dst; int sb;
    if (row < 6144) {
        int b = row / 1536, t3 = row % 1536;
        int br = t3 >> 9, t = t3 & 511;
        const float* xs = (br == 0) ? x1 : ((br == 1) ? x2 : x3);
        src = xs + ((size_t)b * TSEQ + t) * DD;
        dst = hq + (size_t)row * DD;
        sb = br * 4 + b;
    } else {
        int idx = row - 6144;
        src = xf + (size_t)idx * DD;
        dst = hx + (size_t)idx * DD;
        sb = 12 + (idx >> 9);
    }
    float4 x = ((const float4*)src)[tid];
    float s = x.x + x.y + x.z + x.w;
    float q = x.x * x.x + x.y * x.y + x.z * x.z + x.w * x.w;
    for (int o = 1; o < 64; o <<= 1) { s += __shfl_xor(s, o, 64); q += __shfl_xor(q, o, 64); }
    int lane = tid & 63, wid = tid >> 6;
    if (lane == 0) { rs[wid] = s; rq[wid] = q; }
    __syncthreads();
    float S = rs[0] + rs[1] + rs[2] + rs[3];
    float Q = rq[0] + rq[1] + rq[2] + rq[3];
    float mu = S * (1.f / DD);
    float var = Q * (1.f / DD) - mu * mu;
    float rstd = rsqrtf(var + 1e-6f);
    float4 sc = ((const float4*)(scaleB + (size_t)sb * DD))[tid];
    float4 sh = ((const float4*)(shiftB + (size_t)sb * DD))[tid];
    ushort4 o;
    o.x = f2bf((x.x - mu) * rstd * (1.f + sc.x) + sh.x);
    o.y = f2bf((x.y - mu) * rstd * (1.f + sc.y) + sh.y);
    o.z = f2bf((x.z - mu) * rstd * (1.f + sc.z) + sh.z);
    o.w = f2bf((x.w - mu) * rstd * (1.f + sc.w) + sh.w);
    ((ushort4*)dst)[tid] = o;
}

// ---------------------------------------------------------------------------
// K3: fused weight transpose+cvt for all 4 weight tensors.
// grid (16 ktiles, 16 ntiles, 8): z 0-2 q_w, 3 k_w, 4 v_w, 5-7 out_w
// ---------------------------------------------------------------------------
__global__ __launch_bounds__(256) void tw_all_kernel(
    const float* __restrict__ q_w, const float* __restrict__ k_w,
    const float* __restrict__ v_w, const float* __restrict__ out_w,
    unsigned short* __restrict__ qwt, unsigned short* __restrict__ kwt,
    unsigned short* __restrict__ vwt, unsigned short* __restrict__ owt)
{
    __shared__ __align__(16) unsigned short Ts[64 * 72];
    int k0 = blockIdx.x * 64, n0 = blockIdx.y * 64;
    int z = blockIdx.z;
    const float* in; unsigned short* out;
    if (z < 3)       { in = q_w + (size_t)z * DD * DD;       out = qwt + (size_t)z * DD * DD; }
    else if (z == 3) { in = k_w;                             out = kwt; }
    else if (z == 4) { in = v_w;                             out = vwt; }
    else             { in = out_w + (size_t)(z - 5) * DD * DD; out = owt + (size_t)(z - 5) * DD * DD; }
    int tid = threadIdx.x;
    int r = tid >> 2, c0 = (tid & 3) * 16;
#pragma unroll
    for (int i = 0; i < 4; i++) {
        float4 v = *(const float4*)(in + (size_t)(k0 + r) * DD + n0 + c0 + i * 4);
        Ts[(c0 + i * 4 + 0) * 72 + r] = f2bf(v.x);
        Ts[(c0 + i * 4 + 1) * 72 + r] = f2bf(v.y);
        Ts[(c0 + i * 4 + 2) * 72 + r] = f2bf(v.z);
        Ts[(c0 + i * 4 + 3) * 72 + r] = f2bf(v.w);
    }
    __syncthreads();
#pragma unroll
    for (int i = 0; i < 2; i++) {
        int idx = i * 256 + tid;
        int row = idx >> 3, ko = (idx & 7) * 8;
        *(uint4*)(out + (size_t)(n0 + row) * DD + k0 + ko) =
            *(const uint4*)(Ts + row * 72 + ko);
    }
}

// ---------------------------------------------------------------------------
// GEMM core: 128x128 tile, BK=32, global_load_lds staging, 4 waves 2x2 of 64x64
// ---------------------------------------------------------------------------
__device__ __forceinline__ void gemm_core(
    const unsigned short* __restrict__ A, const unsigned short* __restrict__ W,
    int m0, int n0, unsigned short* As, unsigned short* Bs,
    int tid, f32x4 acc[4][4])
{
    int lane = tid & 63, wid = tid >> 6;
    int fm = lane & 15, quad = lane >> 4;
    int wm = wid >> 1, wn = wid & 1;
    int r0 = tid >> 2, ko = (tid & 3) * 8;
    const unsigned short* Ap0 = A + (size_t)(m0 + r0) * DD + ko;
    const unsigned short* Ap1 = A + (size_t)(m0 + r0 + 64) * DD + ko;
    const unsigned short* Wp0 = W + (size_t)(n0 + r0) * DD + ko;
    const unsigned short* Wp1 = W + (size_t)(n0 + r0 + 64) * DD + ko;
    unsigned short* la0 = As + tid * 8;
    unsigned short* la1 = As + (256 + tid) * 8;
    unsigned short* lb0 = Bs + tid * 8;
    unsigned short* lb1 = Bs + (256 + tid) * 8;
    for (int k0 = 0; k0 < DD; k0 += 32) {
        GLD16(Ap0 + k0, la0);
        GLD16(Ap1 + k0, la1);
        GLD16(Wp0 + k0, lb0);
        GLD16(Wp1 + k0, lb1);
        __syncthreads();
        bf16x8 af[4], bf[4];
#pragma unroll
        for (int mt = 0; mt < 4; mt++)
            af[mt] = *(const bf16x8*)(As + (wm * 64 + mt * 16 + fm) * 32 + quad * 8);
#pragma unroll
        for (int nt = 0; nt < 4; nt++)
            bf[nt] = *(const bf16x8*)(Bs + (wn * 64 + nt * 16 + fm) * 32 + quad * 8);
#pragma unroll
        for (int mt = 0; mt < 4; mt++)
#pragma unroll
            for (int nt = 0; nt < 4; nt++)
                acc[mt][nt] = __builtin_amdgcn_mfma_f32_16x16x32_bf16(af[mt], bf[nt], acc[mt][nt], 0, 0, 0);
        __syncthreads();
    }
}

// ---------------------------------------------------------------------------
// K4: fused Q/K/V projection. grid (8, 80): y<48 Q, y<64 K, else V.
// ---------------------------------------------------------------------------
__global__ __launch_bounds__(256) void qkv_gemm(
    const unsigned short* __restrict__ hq, const unsigned short* __restrict__ hx,
    const unsigned short* __restrict__ qwt, const unsigned short* __restrict__ kwt,
    const unsigned short* __restrict__ vwt,
    const float* __restrict__ q_b, const float* __restrict__ k_b,
    const float* __restrict__ v_b,
    unsigned short* __restrict__ Qb, unsigned short* __restrict__ Kb,
    unsigned short* __restrict__ VT)
{
    __shared__ __align__(16) unsigned short As[128 * 32];
    __shared__ __align__(16) unsigned short Bs[128 * 32];
    int ty = blockIdx.y, n0 = blockIdx.x * 128;
    const unsigned short *A, *W; const float* bias; int mode, m0;
    if (ty < 48) {
        m0 = ty * 128;
        int br = (m0 % 1536) >> 9;
        A = hq; W = qwt + (size_t)br * DD * DD; bias = q_b + (size_t)br * DD; mode = 0;
    } else if (ty < 64) {
        m0 = (ty - 48) * 128; A = hx; W = kwt; bias = k_b; mode = 1;
    } else {
        m0 = (ty - 64) * 128; A = hx; W = vwt; bias = v_b; mode = 2;
    }
    int tid = threadIdx.x, lane = tid & 63, wid = tid >> 6;
    int fm = lane & 15, quad = lane >> 4;
    int wm = wid >> 1, wn = wid & 1;
    f32x4 z = {0.f, 0.f, 0.f, 0.f};
    f32x4 acc[4][4];
#pragma unroll
    for (int mt = 0; mt < 4; mt++)
#pragma unroll
        for (int nt = 0; nt < 4; nt++) acc[mt][nt] = z;
    gemm_core(A, W, m0, n0, As, Bs, tid, acc);
#pragma unroll
    for (int mt = 0; mt < 4; mt++) {
#pragma unroll
        for (int nt = 0; nt < 4; nt++) {
            int c = n0 + wn * 64 + nt * 16 + fm;
            float bv = bias[c];
            int r0 = m0 + wm * 64 + mt * 16 + quad * 4;
            if (mode == 2) {
                int b = r0 >> 9, n = r0 & 511, hh = c >> 6, hd = c & 63;
                ushort4 st;
                st.x = f2bf(acc[mt][nt][0] + bv);
                st.y = f2bf(acc[mt][nt][1] + bv);
                st.z = f2bf(acc[mt][nt][2] + bv);
                st.w = f2bf(acc[mt][nt][3] + bv);
                *(ushort4*)(VT + (((size_t)(b * HH + hh)) * HD + hd) * NSEQ + n) = st;
            } else {
                unsigned short* dst = (mode == 0) ? Qb : Kb;
#pragma unroll
                for (int reg = 0; reg < 4; reg++)
                    dst[(size_t)(r0 + reg) * DD + c] = f2bf(acc[mt][nt][reg] + bv);
            }
        }
    }
}

// ---------------------------------------------------------------------------
// K6: out projection, fp32 out remapped branch-major. grid (8, 48)
// ---------------------------------------------------------------------------
__global__ __launch_bounds__(256) void out_gemm(
    const unsigned short* __restrict__ Ain, const unsigned short* __restrict__ owt,
    const float* __restrict__ out_b, float* __restrict__ outp)
{
    __shared__ __align__(16) unsigned short As[128 * 32];
    __shared__ __align__(16) unsigned short Bs[128 * 32];
    int n0 = blockIdx.x * 128, m0 = blockIdx.y * 128;
    int br = (m0 % 1536) >> 9;
    const unsigned short* W = owt + (size_t)br * DD * DD;
    const float* bias = out_b + (size_t)br * DD;
    int tid = threadIdx.x, lane = tid & 63, wid = tid >> 6;
    int fm = lane & 15, quad = lane >> 4;
    int wm = wid >> 1, wn = wid & 1;
    f32x4 z = {0.f, 0.f, 0.f, 0.f};
    f32x4 acc[4][4];
#pragma unroll
    for (int mt = 0; mt < 4; mt++)
#pragma unroll
        for (int nt = 0; nt < 4; nt++) acc[mt][nt] = z;
    gemm_core(Ain, W, m0, n0, As, Bs, tid, acc);
#pragma unroll
    for (int mt = 0; mt < 4; mt++) {
#pragma unroll
        for (int nt = 0; nt < 4; nt++) {
            int c = n0 + wn * 64 + nt * 16 + fm;
            float bv = bias[c];
            int r0 = m0 + wm * 64 + mt * 16 + quad * 4;
            int b = r0 / 1536, t3 = r0 % 1536, t = t3 & 511;
#pragma unroll
            for (int reg = 0; reg < 4; reg++)
                outp[(size_t)br * (BB * TSEQ * DD) + (size_t)b * (TSEQ * DD)
                     + (size_t)(t + reg) * DD + c] = acc[mt][nt][reg] + bv;
        }
    }
}

// ---------------------------------------------------------------------------
// K5: attention, 32 queries/block, S^T in registers. grid (48, 64)
// ---------------------------------------------------------------------------
__global__ __launch_bounds__(256) void attn_kernel(
    const unsigned short* __restrict__ Qb,
    const unsigned short* __restrict__ Kb,
    const unsigned short* __restrict__ VT,
    const unsigned char* __restrict__ mask,
    unsigned short* __restrict__ attn)
{
    __shared__ __align__(16) unsigned short P[32 * 520];
    __shared__ unsigned long long maskb[8];
    __shared__ float redmax[128];
    __shared__ float redsum[128];
    int bh = blockIdx.y, b = bh >> 4, h = bh & 15;
    int m0 = blockIdx.x * 32;
    int tid = threadIdx.x, lane = tid & 63, w = tid >> 6;
    int fm = lane & 15, quad = lane >> 4;

    {
        const unsigned char* mp = mask + (size_t)b * NSEQ;
        unsigned long long lo = __ballot(mp[w * 64 + lane] != 0);
        unsigned long long hi = __ballot(mp[256 + w * 64 + lane] != 0);
        if (lane == 0) { maskb[w] = lo; maskb[4 + w] = hi; }
    }
    __syncthreads();

    f32x4 z = {0.f, 0.f, 0.f, 0.f};
    f32x4 acc[8][2];
#pragma unroll
    for (int mt = 0; mt < 8; mt++) { acc[mt][0] = z; acc[mt][1] = z; }
    const unsigned short* Kp = Kb + ((size_t)(b * NSEQ + w * 128 + fm)) * DD + h * HD + quad * 8;
    const unsigned short* Qp = Qb + ((size_t)(b * 1536 + m0 + fm)) * DD + h * HD + quad * 8;
#pragma unroll
    for (int kk = 0; kk < 2; kk++) {
        bf16x8 bq0 = *(const bf16x8*)(Qp + kk * 32);
        bf16x8 bq1 = *(const bf16x8*)(Qp + (size_t)16 * DD + kk * 32);
#pragma unroll
        for (int mt = 0; mt < 8; mt++) {
            bf16x8 ak = *(const bf16x8*)(Kp + (size_t)mt * 16 * DD + kk * 32);
            acc[mt][0] = __builtin_amdgcn_mfma_f32_16x16x32_bf16(ak, bq0, acc[mt][0], 0, 0, 0);
            acc[mt][1] = __builtin_amdgcn_mfma_f32_16x16x32_bf16(ak, bq1, acc[mt][1], 0, 0, 0);
        }
    }

    unsigned long long mw0 = maskb[w * 2], mw1 = maskb[w * 2 + 1];
    float cmax0 = -1e30f, cmax1 = -1e30f;
#pragma unroll
    for (int mt = 0; mt < 8; mt++) {
        unsigned long long word = (mt >= 4) ? mw1 : mw0;
        int kb = (w * 128 + mt * 16 + quad * 4) & 63;
#pragma unroll
        for (int reg = 0; reg < 4; reg++) {
            bool msk = (word >> (kb + reg)) & 1ull;
            float v0 = acc[mt][0][reg] * 0.125f;
            float v1 = acc[mt][1][reg] * 0.125f;
            v0 = msk ? -1e30f : v0;
            v1 = msk ? -1e30f : v1;
            acc[mt][0][reg] = v0; acc[mt][1][reg] = v1;
            cmax0 = fmaxf(cmax0, v0); cmax1 = fmaxf(cmax1, v1);
        }
    }
    cmax0 = fmaxf(cmax0, __shfl_xor(cmax0, 16, 64));
    cmax0 = fmaxf(cmax0, __shfl_xor(cmax0, 32, 64));
    cmax1 = fmaxf(cmax1, __shfl_xor(cmax1, 16, 64));
    cmax1 = fmaxf(cmax1, __shfl_xor(cmax1, 32, 64));
    if (quad == 0) { redmax[w * 32 + fm] = cmax0; redmax[w * 32 + 16 + fm] = cmax1; }
    __syncthreads();
    float g0 = fmaxf(fmaxf(redmax[fm], redmax[32 + fm]),
                     fmaxf(redmax[64 + fm], redmax[96 + fm]));
    float g1 = fmaxf(fmaxf(redmax[16 + fm], redmax[48 + fm]),
                     fmaxf(redmax[80 + fm], redmax[112 + fm]));
    float s0 = 0.f, s1 = 0.f;
#pragma unroll
    for (int mt = 0; mt < 8; mt++) {
        float e00 = __expf(acc[mt][0][0] - g0);
        float e01 = __expf(acc[mt][0][1] - g0);
        float e02 = __expf(acc[mt][0][2] - g0);
        float e03 = __expf(acc[mt][0][3] - g0);
        float e10 = __expf(acc[mt][1][0] - g1);
        float e11 = __expf(acc[mt][1][1] - g1);
        float e12 = __expf(acc[mt][1][2] - g1);
        float e13 = __expf(acc[mt][1][3] - g1);
        s0 += (e00 + e01) + (e02 + e03);
        s1 += (e10 + e11) + (e12 + e13);
        ushort4 p0, p1;
        p0.x = f2bf(e00); p0.y = f2bf(e01); p0.z = f2bf(e02); p0.w = f2bf(e03);
        p1.x = f2bf(e10); p1.y = f2bf(e11); p1.z = f2bf(e12); p1.w = f2bf(e13);
        int kb = w * 128 + mt * 16 + quad * 4;
        *(ushort4*)(P + (size_t)fm * 520 + kb) = p0;
        *(ushort4*)(P + (size_t)(16 + fm) * 520 + kb) = p1;
    }
    s0 += __shfl_xor(s0, 16, 64); s0 += __shfl_xor(s0, 32, 64);
    s1 += __shfl_xor(s1, 16, 64); s1 += __shfl_xor(s1, 32, 64);
    if (quad == 0) { redsum[w * 32 + fm] = s0; redsum[w * 32 + 16 + fm] = s1; }
    __syncthreads();

    float inv0 = 1.f / (redsum[fm] + redsum[32 + fm] + redsum[64 + fm] + redsum[96 + fm]);
    float inv1 = 1.f / (redsum[16 + fm] + redsum[48 + fm] + redsum[80 + fm] + redsum[112 + fm]);
    f32x4 o0 = z, o1 = z;
    const unsigned short* Vp = VT + ((size_t)(bh * HD + w * 16 + fm)) * NSEQ + quad * 8;
    const unsigned short* Pp0 = P + (size_t)fm * 520 + quad * 8;
    const unsigned short* Pp1 = P + (size_t)(16 + fm) * 520 + quad * 8;
#pragma unroll
    for (int kk = 0; kk < 16; kk++) {
        bf16x8 av = *(const bf16x8*)(Vp + kk * 32);
        bf16x8 p0 = *(const bf16x8*)(Pp0 + kk * 32);
        bf16x8 p1 = *(const bf16x8*)(Pp1 + kk * 32);
        o0 = __builtin_amdgcn_mfma_f32_16x16x32_bf16(av, p0, o0, 0, 0, 0);
        o1 = __builtin_amdgcn_mfma_f32_16x16x32_bf16(av, p1, o1, 0, 0, 0);
    }
    ushort4 r0, r1;
    r0.x = f2bf(o0[0] * inv0); r0.y = f2bf(o0[1] * inv0);
    r0.z = f2bf(o0[2] * inv0); r0.w = f2bf(o0[3] * inv0);
    r1.x = f2bf(o1[0] * inv1); r1.y = f2bf(o1[1] * inv1);
    r1.z = f2bf(o1[2] * inv1); r1.w = f2bf(o1[3] * inv1);
    *(ushort4*)(attn + ((size_t)(b * 1536 + m0 + fm)) * DD + h * HD + w * 16 + quad * 4) = r0;
    *(ushort4*)(attn + ((size_t)(b * 1536 + m0 + 16 + fm)) * DD + h * HD + w * 16 + quad * 4) = r1;
}

// ---------------------------------------------------------------------------
extern "C" void kernel_launch(void* const* d_in, const int* in_sizes, int n_in,
                              void* d_out, int out_size, void* d_ws, size_t ws_size,
                              hipStream_t stream)
{
    const float* x1   = (const float*)d_in[0];
    const float* x2   = (const float*)d_in[1];
    const float* x3   = (const float*)d_in[2];
    const float* xf   = (const float*)d_in[3];
    const float* emb  = (const float*)d_in[4];
    const unsigned char* mask = (const unsigned char*)d_in[5];
    const float* adaln_w = (const float*)d_in[6];
    const float* adaln_b = (const float*)d_in[7];
    const float* xf_w = (const float*)d_in[8];
    const float* xf_b = (const float*)d_in[9];
    const float* q_w  = (const float*)d_in[10];
    const float* q_b  = (const float*)d_in[11];
    const float* k_w  = (const float*)d_in[12];
    const float* k_b  = (const float*)d_in[13];
    const float* v_w  = (const float*)d_in[14];
    const float* v_b  = (const float*)d_in[15];
    const float* out_w = (const float*)d_in[16];
    const float* out_b = (const float*)d_in[17];

    char* ws = (char*)d_ws;
    float* scaleB        = (float*)(ws + 0);
    float* shiftB        = (float*)(ws + 65536);
    unsigned short* hq   = (unsigned short*)(ws + 131072);     // 12.58 MB (reused for attn out)
    unsigned short* hx   = (unsigned short*)(ws + 12713984);   // 4.19 MB
    unsigned short* Qb   = (unsigned short*)(ws + 16908288);   // 12.58 MB
    unsigned short* Kb   = (unsigned short*)(ws + 29491200);   // 4.19 MB
    unsigned short* VT   = (unsigned short*)(ws + 33685504);   // 4.19 MB
    unsigned short* qwt  = (unsigned short*)(ws + 37879808);   // 6.29 MB
    unsigned short* kwt  = (unsigned short*)(ws + 44171264);   // 2.10 MB
    unsigned short* vwt  = (unsigned short*)(ws + 46268416);   // 2.10 MB
    unsigned short* owt  = (unsigned short*)(ws + 48365568);   // 6.29 MB (end ~54.7 MB)

    tw_all_kernel<<<dim3(16, 16, 8), 256, 0, stream>>>(q_w, k_w, v_w, out_w,
                                                       qwt, kwt, vwt, owt);
    adaln_kernel<<<dim3(64, 4), 256, 0, stream>>>(emb, adaln_w, adaln_b, xf_w, xf_b,
                                                  scaleB, shiftB);
    ln_mod_kernel<<<8192, 256, 0, stream>>>(x1, x2, x3, xf, scaleB, shiftB, hq, hx);
    qkv_gemm<<<dim3(8, 80), 256, 0, stream>>>(hq, hx, qwt, kwt, vwt, q_b, k_b, v_b,
                                              Qb, Kb, VT);
    attn_kernel<<<dim3(48, 64), 256, 0, stream>>>(Qb, Kb, VT, mask, hq);
    out_gemm<<<dim3(8, 48), 256, 0, stream>>>(hq, owt, out_b, (float*)d_out);
}